// Round 10
// baseline (204.665 us; speedup 1.0000x reference)
//
#include <hip/hip_runtime.h>
#include <hip/hip_bf16.h>
#include <hip/hip_fp16.h>
#include <math.h>

#define LQ_  2048
#define LK_  2048
#define D_   128
#define B_   16
#define LN_EPS 1e-5f
#define TK_  32
#define NTILE (LK_ / TK_)
#define HTILE (NTILE / 2)

// Workspace layout:
//   [0, 8 MB):        K images (fp16, swizzled)
//   [8 MB, 16 MB):    Vt images (bf16-pair)
//   [16 MB, +33.55M): O partials: [pair][h][64][128] f32   (pair = b*32+qslot)
//   then              l partials: [pair][h][64] f32
#define KH_TILE_US 4096          // 32 rows x 128 d fp16 (8192 B)
#define VT_TILE_U  2048          // 128 d x 16 slot uint (8192 B)
#define KH_BYTES   ((size_t)B_ * NTILE * KH_TILE_US * 2)   // 8,388,608
#define VT_OFF     KH_BYTES                                 // 8,388,608
#define OP_OFF     (2 * KH_BYTES)                           // 16,777,216
#define OP_BYTES   ((size_t)512 * 2 * 64 * 128 * 4)         // 33,554,432
#define LW_OFF     (OP_OFF + OP_BYTES)                      // 50,331,648
// total ws: 50,593,792 B

typedef __attribute__((ext_vector_type(8))) short short8;
typedef __attribute__((ext_vector_type(8))) _Float16 half8;
typedef __attribute__((ext_vector_type(4))) float f32x4;

union FragU { uint4 u4; short8 s8; half8 h8; unsigned int u[4]; };

__device__ __forceinline__ unsigned int pk_bf16(float a, float b) {
  __hip_bfloat162 h = __float22bfloat162_rn(make_float2(a, b));
  unsigned int u;
  __builtin_memcpy(&u, &h, 4);
  return u;
}
__device__ __forceinline__ unsigned int pk_f16(float a, float b) {
  __half2 h = __floats2half2_rn(a, b);
  unsigned int u;
  __builtin_memcpy(&u, &h, 4);
  return u;
}
__device__ __forceinline__ float f16_lo(unsigned int u) {
  unsigned short s = (unsigned short)(u & 0xffffu);
  __half h; __builtin_memcpy(&h, &s, 2); return __half2float(h);
}
__device__ __forceinline__ float f16_hi(unsigned int u) {
  unsigned short s = (unsigned short)(u >> 16);
  __half h; __builtin_memcpy(&h, &s, 2); return __half2float(h);
}

// K tiles: ushort [32 rows][128 d], 16B(8-elem)-chunk XOR swizzle by row.
__device__ __forceinline__ int idxK(int row, int d) {
  return row * 128 + ((((d >> 3) ^ row) & 15) << 3) + (d & 7);
}
// Vt: uint [128 d][16 slots]; 16B chunk rotation p = (g + (d>>1)) & 3.
// Slot->kp mapping is the PV-permuted order (see conv_kv emit).
__device__ __forceinline__ int idxVt(int d, int slot) {
  return d * 16 + ((((slot >> 2) + (d >> 1)) & 3) << 2) + (slot & 3);
}

// Barrier that drains this wave's tile-stage DMA (stage ops are the oldest;
// the 2 newest vm ops -- prefetched mask float4 loads -- stay in flight).
__device__ __forceinline__ void barrier_stage() {
  asm volatile("s_waitcnt vmcnt(2) lgkmcnt(0)\n\ts_barrier" ::: "memory");
}

__device__ __forceinline__ void gld_lds16(const void* g, void* l) {
  __builtin_amdgcn_global_load_lds((const __attribute__((address_space(1))) void*)g,
                                   (__attribute__((address_space(3))) void*)l, 16, 0, 0);
}

// ---------------- pre-pass: K -> fp16 swizzled, V -> bf16-pair Vt ----------
__global__ __launch_bounds__(256) void conv_kv(
    const float* __restrict__ kg, const float* __restrict__ vg,
    unsigned short* __restrict__ khg, unsigned int* __restrict__ vtg)
{
  __shared__ float Vlt[128 * 33];   // V tile transposed, +1-pad rows
  const int tid = threadIdx.x;
  const int blk = blockIdx.x;          // b*64 + t
  const int b = blk >> 6;
  const int t = blk & 63;

  const float* ks = kg + ((size_t)b * LK_ + t * 32) * D_;
  const float* vs = vg + ((size_t)b * LK_ + t * 32) * D_;
  unsigned short* kh = khg + (size_t)blk * KH_TILE_US;
  unsigned int*   vt = vtg + (size_t)blk * VT_TILE_U;

  // K: 512 (row, 8-chunk) items, 2 per thread; coalesced reads, 16B swizzled writes
#pragma unroll
  for (int it = 0; it < 2; it++) {
    const int item = tid + it * 256;
    const int row = item >> 4;
    const int c8  = item & 15;
    const float* p = ks + row * D_ + c8 * 8;
    float4 x = *(const float4*)(p);
    float4 y = *(const float4*)(p + 4);
    FragU H;
    H.u[0] = pk_f16(x.x, x.y); H.u[1] = pk_f16(x.z, x.w);
    H.u[2] = pk_f16(y.x, y.y); H.u[3] = pk_f16(y.z, y.w);
    *(uint4*)&kh[idxK(row, c8 * 8)] = H.u4;
  }

  // V tile -> LDS transposed (coalesced global reads).
#pragma unroll
  for (int i = 0; i < 4; i++) {
    const int item = tid + i * 256;
    const int r = item >> 5, c4 = item & 31;
    float4 x = *(const float4*)&vs[r * D_ + c4 * 4];
    Vlt[(c4 * 4 + 0) * 33 + r] = x.x;
    Vlt[(c4 * 4 + 1) * 33 + r] = x.y;
    Vlt[(c4 * 4 + 2) * 33 + r] = x.z;
    Vlt[(c4 * 4 + 3) * 33 + r] = x.w;
  }
  __syncthreads();

  // Emit Vt image linearly (coalesced writes); inverse-map phys slot -> kp.
#pragma unroll
  for (int i = 0; i < 8; i++) {
    const int o = tid + i * 256;
    const int d = o >> 4, sp = o & 15;
    const int gl = ((sp >> 2) - (d >> 1)) & 3;
    const int c  = sp & 3;
    const int kp = 2 * gl + ((c >> 1) << 3) + (c & 1);
    vt[o] = pk_bf16(Vlt[d * 33 + 2 * kp], Vlt[d * 33 + 2 * kp + 1]);
  }
}

// ---------------- main fused attention (k-half partials) ----------------
// Stage one tile's images into LDS via global_load_lds: 4 x 1KiB per wave,
// 4 cooperating waves cover 8 KB K + 8 KB Vt.
__device__ __forceinline__ void stage_tile(int w, int lane,
    const unsigned short* khT, const unsigned int* vtT,
    int tile, char* khs, char* vts)
{
  const char* gkh = (const char*)(khT + (size_t)tile * KH_TILE_US);
  const char* gvt = (const char*)(vtT + (size_t)tile * VT_TILE_U);
#pragma unroll
  for (int c = 0; c < 2; c++) {
    const int off = (w + 4 * c) << 10;            // 1 KiB chunks
    gld_lds16(gkh + off + lane * 16, khs + off);
    gld_lds16(gvt + off + lane * 16, vts + off);
  }
}

__global__ __launch_bounds__(256, 4) void attn_part(
    const float* __restrict__ qg, const float* __restrict__ maskg,
    const unsigned short* __restrict__ khg, const unsigned int* __restrict__ vtg,
    float* __restrict__ opg, float* __restrict__ lwg)
{
  __shared__ unsigned short KhS[2][32 * 128];   // 16 KB (fp16)
  __shared__ unsigned int   VtW[2][128 * 16];   // 16 KB
  // total 32,768 B -> 4 blocks/CU (grid 1024 = 4/CU, 16 waves/CU)

  const int tid  = threadIdx.x;
  const int w    = tid >> 6;     // wave owns q-rows [q0 + w*16, +16)
  const int lane = tid & 63;
  const int quad = lane >> 4;
  const int lr   = lane & 15;

  // XCD swizzle: 128 slots per XCD = 2 batches x 32 q-slots x 2 k-halves.
  const int id   = blockIdx.x;   // 0..1023
  const int xcd  = id & 7;
  const int slot = id >> 3;      // 0..127
  const int b    = xcd * 2 + (slot >> 6);
  const int rem  = slot & 63;
  const int h    = rem >> 5;     // k-half: tiles [h*32, h*32+32)
  const int qs   = rem & 31;
  const int q0   = qs * 64;
  const int pair = b * 32 + qs;  // 0..511

  const int kt0 = h * HTILE, kt1 = kt0 + HTILE;

  const unsigned short* khT = khg + (size_t)b * NTILE * KH_TILE_US;
  const unsigned int*   vtT = vtg + (size_t)b * NTILE * VT_TILE_U;

  // mask row for this lane's q-row (= lr in swapped layout), quad's k-cols.
  const float* mrow = maskg + (size_t)(q0 + w * 16 + lr) * LK_ + quad * 4;

  // ---- issue first-tile stage DMA + mask prefetch (fly during Q build) ----
  stage_tile(w, lane, khT, vtT, kt0, (char*)&KhS[0][0], (char*)&VtW[0][0]);
  float4 mA[2], mB[2];
  mA[0] = *(const float4*)(mrow + kt0 * TK_);
  mA[1] = *(const float4*)(mrow + kt0 * TK_ + 16);

  // ---- Q fragments (fp16 hi/lo) for this wave's 16 rows; row = w*16 + lr ----
  half8 qh[4], ql[4];
  {
    const float* qrow = qg + ((size_t)b * LQ_ + q0 + w * 16 + lr) * D_ + quad * 8;
#pragma unroll
    for (int c = 0; c < 4; c++) {
      float4 x = *(const float4*)(qrow + c * 32);
      float4 y = *(const float4*)(qrow + c * 32 + 4);
      FragU H, L;
      H.u[0] = pk_f16(x.x, x.y); H.u[1] = pk_f16(x.z, x.w);
      H.u[2] = pk_f16(y.x, y.y); H.u[3] = pk_f16(y.z, y.w);
      L.u[0] = pk_f16(x.x - f16_lo(H.u[0]), x.y - f16_hi(H.u[0]));
      L.u[1] = pk_f16(x.z - f16_lo(H.u[1]), x.w - f16_hi(H.u[1]));
      L.u[2] = pk_f16(y.x - f16_lo(H.u[2]), y.y - f16_hi(H.u[2]));
      L.u[3] = pk_f16(y.z - f16_lo(H.u[3]), y.w - f16_hi(H.u[3]));
      qh[c] = H.h8; ql[c] = L.h8;
    }
  }

  float l_part = 0.f;            // sum of p over this lane's k-cols, row = lr
  f32x4 o[8];                    // [nb]: q-row = quad*4+reg, d = nb*16+lr
  const f32x4 zf = {0.f, 0.f, 0.f, 0.f};
#pragma unroll
  for (int n = 0; n < 8; n++) o[n] = zf;

  // One tile body (round-8 form). cur is a literal (0/1); mu holds mask(kt);
  // mask(kt+1) is prefetched into mp (named regs -> counted vmcnt at use).
  auto body = [&](int kt, int cur, float4 (&mu)[2], float4 (&mp)[2])
      __attribute__((always_inline)) -> void {
    const unsigned short* khc = &KhS[cur][0];
    const unsigned int*   vtc = &VtW[cur][0];

    // All waves past previous tile's LDS reads; this wave's stage(kt) done.
    // The 2 newest vm ops (mask(kt) float4 loads) stay in flight.
    barrier_stage();

    // ---- issue NEXT tile stage (4 vm) + NEXT mask prefetch (2 vm) ----
    if (kt + 1 < kt1) {
      stage_tile(w, lane, khT, vtT, kt + 1,
                 (char*)&KhS[cur ^ 1][0], (char*)&VtW[cur ^ 1][0]);
      mp[0] = *(const float4*)(mrow + (kt + 1) * TK_);
      mp[1] = *(const float4*)(mrow + (kt + 1) * TK_ + 16);
    }

    // ---- S^T = K Q^T (fp16 2-term, swapped operands: A=K, B=Q) ----
    // sacc[ct] lane layout: k = ct*16 + quad*4 + reg, q-row = lr.
    f32x4 sH[2], sL[2];
    sH[0] = zf; sH[1] = zf; sL[0] = zf; sL[1] = zf;
#pragma unroll
    for (int c = 0; c < 4; c++)
#pragma unroll
      for (int ct = 0; ct < 2; ct++) {
        FragU kh;
        kh.u4 = *(const uint4*)&khc[idxK(ct * 16 + lr, c * 32 + quad * 8)];
        sH[ct] = __builtin_amdgcn_mfma_f32_16x16x32_f16(kh.h8, qh[c], sH[ct], 0, 0, 0);
        sL[ct] = __builtin_amdgcn_mfma_f32_16x16x32_f16(kh.h8, ql[c], sL[ct], 0, 0, 0);
      }

    // ---- Bv reads: LDS latency overlaps the exp chain ----
    FragU Bv[8];
#pragma unroll
    for (int nb = 0; nb < 8; nb++)
      Bv[nb].u4 = *(const uint4*)&vtc[idxVt(nb * 16 + lr, quad * 4)];

    // ---- max-free softmax, fully in registers ----
    float pv[2][4];
#pragma unroll
    for (int ct = 0; ct < 2; ct++) {
      const float* mf = (const float*)&mu[ct];
#pragma unroll
      for (int reg = 0; reg < 4; reg++) {
        float p = __expf(sH[ct][reg] + sL[ct][reg] + mf[reg]);
        l_part += p;
        pv[ct][reg] = p;
      }
    }

    // ---- pack P -> PV A-fragment in-lane (zero shuffles, zero LDS) ----
    FragU A;
    A.u[0] = pk_bf16(pv[0][0], pv[0][1]);
    A.u[1] = pk_bf16(pv[0][2], pv[0][3]);
    A.u[2] = pk_bf16(pv[1][0], pv[1][1]);
    A.u[3] = pk_bf16(pv[1][2], pv[1][3]);

    // ---- O += P * V: 8 independent MFMAs over d ----
#pragma unroll
    for (int nb = 0; nb < 8; nb++)
      o[nb] = __builtin_amdgcn_mfma_f32_16x16x32_bf16(A.s8, Bv[nb].s8, o[nb], 0, 0, 0);
  };

  for (int kt = kt0; kt < kt1; kt += 2) {
    body(kt,     0, mA, mB);   // consumes mask in mA, prefetches into mB
    body(kt + 1, 1, mB, mA);   // consumes mask in mB, prefetches into mA
  }

  // ---- epilogue: write raw partials (no normalize -- merge kernel does) ----
  float lt = l_part;
  lt += __shfl_xor(lt, 16, 64);
  lt += __shfl_xor(lt, 32, 64);          // lt = l for q-row (w*16+lr), all quads

  float* Lp = lwg + ((size_t)pair * 2 + h) * 64;
  if (quad == 0) Lp[w * 16 + lr] = lt;

  float* Op = opg + ((size_t)pair * 2 + h) * (64 * 128);
#pragma unroll
  for (int reg = 0; reg < 4; reg++) {
    float* orow = Op + (size_t)(w * 16 + quad * 4 + reg) * 128 + lr;
#pragma unroll
    for (int nb = 0; nb < 8; nb++)
      orow[nb * 16] = o[nb][reg];
  }
}

// ---------------- merge + LayerNorm ----------------
// 512 blocks (one per pair), 256 threads. Fully coalesced: thread t handles
// float4 positions t + i*256 of the 64x128 row-major partial images.
__global__ __launch_bounds__(256) void merge_ln(
    const float* __restrict__ opg, const float* __restrict__ lwg,
    const float* __restrict__ gammag, const float* __restrict__ betag,
    float* __restrict__ outg)
{
  const int tid  = threadIdx.x;
  const int pair = blockIdx.x;           // 0..511
  const int b    = pair >> 5;
  const int q0   = (pair & 31) * 64;

  const float4* P0 = (const float4*)(opg + (size_t)pair * 2 * (64 * 128));
  const float4* P1 = P0 + 2048;
  const float*  L0 = lwg + (size_t)pair * 2 * 64;
  const float*  L1 = L0 + 64;

  float4* outf4 = (float4*)(outg + ((size_t)b * LQ_ + q0) * D_);

#pragma unroll
  for (int i = 0; i < 8; i++) {
    const int pos = tid + i * 256;       // 0..2047
    const int row = pos >> 5;            // 32 float4 per row
    const int c4  = pos & 31;

    float4 a = P0[pos], c = P1[pos];
    const float invl = 1.f / (L0[row] + L1[row]);
    float v0 = (a.x + c.x) * invl;
    float v1 = (a.y + c.y) * invl;
    float v2 = (a.z + c.z) * invl;
    float v3 = (a.w + c.w) * invl;

    // LN moments: each row is held by a 32-lane half-wave (rows map to
    // lanes 0-31 / 32-63 of each wave at every i) -> shfl_xor 1..16 stays
    // within the half-wave.
    float s1 = v0 + v1 + v2 + v3;
    float s2 = v0 * v0 + v1 * v1 + v2 * v2 + v3 * v3;
#pragma unroll
    for (int m = 1; m <= 16; m <<= 1) {
      s1 += __shfl_xor(s1, m, 64);
      s2 += __shfl_xor(s2, m, 64);
    }
    const float mean = s1 * (1.f / 128.f);
    const float var  = s2 * (1.f / 128.f) - mean * mean;
    const float rstd = rsqrtf(var + LN_EPS);

    const float4 g  = *(const float4*)&gammag[c4 * 4];
    const float4 be = *(const float4*)&betag[c4 * 4];
    float4 r;
    r.x = (v0 - mean) * rstd * g.x + be.x;
    r.y = (v1 - mean) * rstd * g.y + be.y;
    r.z = (v2 - mean) * rstd * g.z + be.z;
    r.w = (v3 - mean) * rstd * g.w + be.w;
    outf4[pos] = r;
  }
}

extern "C" void kernel_launch(void* const* d_in, const int* in_sizes, int n_in,
                              void* d_out, int out_size, void* d_ws, size_t ws_size,
                              hipStream_t stream) {
  const float* q     = (const float*)d_in[0];
  const float* k     = (const float*)d_in[1];
  const float* v     = (const float*)d_in[2];
  const float* mask  = (const float*)d_in[3];
  const float* gamma = (const float*)d_in[4];
  const float* beta  = (const float*)d_in[5];
  float* out = (float*)d_out;

  unsigned short* khg = (unsigned short*)d_ws;
  unsigned int*   vtg = (unsigned int*)((char*)d_ws + VT_OFF);
  float*          opg = (float*)((char*)d_ws + OP_OFF);
  float*          lwg = (float*)((char*)d_ws + LW_OFF);

  conv_kv<<<dim3(B_ * NTILE), dim3(256), 0, stream>>>(k, v, khg, vtg);
  attn_part<<<dim3(1024), dim3(256), 0, stream>>>(q, mask, khg, vtg, opg, lwg);
  merge_ln<<<dim3(512), dim3(256), 0, stream>>>(opg, lwg, gamma, beta, out);
}

// Round 11
// 202.546 us; speedup vs baseline: 1.0105x; 1.0105x over previous
//
#include <hip/hip_runtime.h>
#include <hip/hip_bf16.h>
#include <hip/hip_fp16.h>
#include <math.h>

#define LQ_  2048
#define LK_  2048
#define D_   128
#define B_   16
#define LN_EPS 1e-5f
#define TK_  32
#define NTILE (LK_ / TK_)

// Workspace: fragment-major K images + Vt images, 8192 B per tile each.
//   K tile image: 8 chunks (f = c*2+ct) x 64 lanes x 16 B; lane(quad,lr)
//     chunk f holds K[ct*16+lr][c*32+quad*8 .. +8] as 8 fp16.
//   Vt tile image: uint [128 d][16 slots], PV-permuted slot order (round-8).
#define KH_TILE_B  8192
#define VT_TILE_B  8192
#define KH_BYTES   ((size_t)B_ * NTILE * KH_TILE_B)         // 8,388,608
#define VT_OFF     KH_BYTES                                  // 8,388,608
// total ws: 16,777,216 B

typedef __attribute__((ext_vector_type(8))) short short8;
typedef __attribute__((ext_vector_type(8))) _Float16 half8;
typedef __attribute__((ext_vector_type(4))) float f32x4;

union FragU { uint4 u4; short8 s8; half8 h8; unsigned int u[4]; };

__device__ __forceinline__ unsigned int pk_bf16(float a, float b) {
  __hip_bfloat162 h = __float22bfloat162_rn(make_float2(a, b));
  unsigned int u;
  __builtin_memcpy(&u, &h, 4);
  return u;
}
__device__ __forceinline__ unsigned int pk_f16(float a, float b) {
  __half2 h = __floats2half2_rn(a, b);
  unsigned int u;
  __builtin_memcpy(&u, &h, 4);
  return u;
}
__device__ __forceinline__ float f16_lo(unsigned int u) {
  unsigned short s = (unsigned short)(u & 0xffffu);
  __half h; __builtin_memcpy(&h, &s, 2); return __half2float(h);
}
__device__ __forceinline__ float f16_hi(unsigned int u) {
  unsigned short s = (unsigned short)(u >> 16);
  __half h; __builtin_memcpy(&h, &s, 2); return __half2float(h);
}

// Vt dword index (identical math to round 8; now a global-memory offset).
__device__ __forceinline__ int idxVt(int d, int slot) {
  return d * 16 + ((((slot >> 2) + (d >> 1)) & 3) << 2) + (slot & 3);
}

// ---------------- pre-pass: K -> fp16 fragment-major, V -> bf16-pair Vt ----
__global__ __launch_bounds__(256) void conv_kv(
    const float* __restrict__ kg, const float* __restrict__ vg,
    unsigned short* __restrict__ khg, unsigned int* __restrict__ vtg)
{
  __shared__ float Vlt[128 * 33];   // V tile transposed, +1-pad rows
  const int tid = threadIdx.x;
  const int blk = blockIdx.x;          // b*64 + t
  const int b = blk >> 6;
  const int t = blk & 63;

  const float* ks = kg + ((size_t)b * LK_ + t * 32) * D_;
  const float* vs = vg + ((size_t)b * LK_ + t * 32) * D_;
  unsigned short* kh = khg + (size_t)blk * (KH_TILE_B / 2);
  unsigned int*   vt = vtg + (size_t)blk * (VT_TILE_B / 4);

  // K: 512 (row, 8-chunk) items; coalesced 32B reads, fragment-major writes.
#pragma unroll
  for (int it = 0; it < 2; it++) {
    const int item = tid + it * 256;
    const int row = item >> 4;          // 0..31
    const int c8  = item & 15;          // d-chunk of 8
    const float* p = ks + row * D_ + c8 * 8;
    float4 x = *(const float4*)(p);
    float4 y = *(const float4*)(p + 4);
    FragU H;
    H.u[0] = pk_f16(x.x, x.y); H.u[1] = pk_f16(x.z, x.w);
    H.u[2] = pk_f16(y.x, y.y); H.u[3] = pk_f16(y.z, y.w);
    const int c = c8 >> 2, quad = c8 & 3;
    const int ct = row >> 4, lr = row & 15;
    // ushort index: chunk (c*2+ct) of 512 ushorts + lane(quad*16+lr) * 8
    *(uint4*)&kh[((c * 2 + ct) << 9) + (quad * 16 + lr) * 8] = H.u4;
  }

  // V tile -> LDS transposed (coalesced global reads).
#pragma unroll
  for (int i = 0; i < 4; i++) {
    const int item = tid + i * 256;
    const int r = item >> 5, c4 = item & 31;
    float4 x = *(const float4*)&vs[r * D_ + c4 * 4];
    Vlt[(c4 * 4 + 0) * 33 + r] = x.x;
    Vlt[(c4 * 4 + 1) * 33 + r] = x.y;
    Vlt[(c4 * 4 + 2) * 33 + r] = x.z;
    Vlt[(c4 * 4 + 3) * 33 + r] = x.w;
  }
  __syncthreads();

  // Emit Vt image linearly (coalesced writes); inverse-map phys slot -> kp.
#pragma unroll
  for (int i = 0; i < 8; i++) {
    const int o = tid + i * 256;
    const int d = o >> 4, sp = o & 15;
    const int gl = ((sp >> 2) - (d >> 1)) & 3;
    const int c  = sp & 3;
    const int kp = 2 * gl + ((c >> 1) << 3) + (c & 1);
    vt[o] = pk_bf16(Vlt[d * 33 + 2 * kp], Vlt[d * 33 + 2 * kp + 1]);
  }
}

// ---------------- main fused attention + LN: no LDS, no barriers ----------
__global__ __launch_bounds__(256, 2) void attn_ln_mfma(
    const float* __restrict__ qg, const float* __restrict__ maskg,
    const float* __restrict__ gammag, const float* __restrict__ betag,
    const unsigned short* __restrict__ khg, const unsigned int* __restrict__ vtg,
    float* __restrict__ outg)
{
  const int tid  = threadIdx.x;
  const int w    = tid >> 6;     // wave owns q-rows [q0 + w*16, +16)
  const int lane = tid & 63;
  const int quad = lane >> 4;
  const int lr   = lane & 15;

  // XCD swizzle: blocks on XCD x serve batches {2x,2x+1} -> K/V L2-resident.
  const int id   = blockIdx.x;
  const int xcd  = id & 7;
  const int slot = id >> 3;
  const int b    = xcd * 2 + (slot >> 5);
  const int q0   = (slot & 31) * 64;

  const char* khT = (const char*)khg + (size_t)b * NTILE * KH_TILE_B;
  const char* vtT = (const char*)vtg + (size_t)b * NTILE * VT_TILE_B;

  // Per-lane fragment byte offsets (loop-invariant).
  const int kOff = lane * 16;
  const int vOff = idxVt(lr, quad * 4) * 4;   // nb=0; +1024 B per nb

  // mask row for this lane's q-row (= lr in swapped layout), quad's k-cols.
  const float* mrow = maskg + (size_t)(q0 + w * 16 + lr) * LK_ + quad * 4;

  FragU kfA[8], kfB[8], vf[8];
  float4 mA[2], mB[2];

  auto loadK = [&](int kt, FragU (&kf)[8]) __attribute__((always_inline)) {
    const char* p = khT + (size_t)kt * KH_TILE_B + kOff;
#pragma unroll
    for (int f = 0; f < 8; f++) kf[f].u4 = *(const uint4*)(p + (f << 10));
  };
  auto loadV = [&](int kt) __attribute__((always_inline)) {
    const char* p = vtT + (size_t)kt * VT_TILE_B + vOff;
#pragma unroll
    for (int nb = 0; nb < 8; nb++) vf[nb].u4 = *(const uint4*)(p + (nb << 10));
  };
  auto loadM = [&](int kt, float4 (&m)[2]) __attribute__((always_inline)) {
    m[0] = *(const float4*)(mrow + kt * TK_);
    m[1] = *(const float4*)(mrow + kt * TK_ + 16);
  };

  // ---- prologue: issue tile-0 loads, then build Q fragments ----
  loadK(0, kfA);
  loadM(0, mA);
  loadV(0);

  half8 qh[4], ql[4];
  {
    const float* qrow = qg + ((size_t)b * LQ_ + q0 + w * 16 + lr) * D_ + quad * 8;
#pragma unroll
    for (int c = 0; c < 4; c++) {
      float4 x = *(const float4*)(qrow + c * 32);
      float4 y = *(const float4*)(qrow + c * 32 + 4);
      FragU H, L;
      H.u[0] = pk_f16(x.x, x.y); H.u[1] = pk_f16(x.z, x.w);
      H.u[2] = pk_f16(y.x, y.y); H.u[3] = pk_f16(y.z, y.w);
      L.u[0] = pk_f16(x.x - f16_lo(H.u[0]), x.y - f16_hi(H.u[0]));
      L.u[1] = pk_f16(x.z - f16_lo(H.u[1]), x.w - f16_hi(H.u[1]));
      L.u[2] = pk_f16(y.x - f16_lo(H.u[2]), y.y - f16_hi(H.u[2]));
      L.u[3] = pk_f16(y.z - f16_lo(H.u[3]), y.w - f16_hi(H.u[3]));
      qh[c] = H.h8; ql[c] = L.h8;
    }
  }

  float l_part = 0.f;            // sum of p over this lane's k-cols, row = lr
  f32x4 o[8];                    // [nb]: q-row = quad*4+reg, d = nb*16+lr
  const f32x4 zf = {0.f, 0.f, 0.f, 0.f};
#pragma unroll
  for (int n = 0; n < 8; n++) o[n] = zf;

  // Body: consumes K in kfC, prefetches K(kt+1) into kfN (double-buffered,
  // issued a full body ahead); mask mu consumed / mp prefetched; V single-
  // buffer rotated (issued after PV consumed it). Issue order [K][M][V]
  // makes every compiler wait counted (vmcnt 18/16/8), never 0.
  auto body = [&](int kt, FragU (&kfC)[8], FragU (&kfN)[8],
                  float4 (&mu)[2], float4 (&mp)[2])
      __attribute__((always_inline)) -> void {
    if (kt + 1 < NTILE) loadK(kt + 1, kfN);
    __builtin_amdgcn_sched_barrier(0);

    // ---- S^T = K Q^T (fp16 2-term, swapped operands: A=K, B=Q) ----
    // sacc[ct] lane layout: k = ct*16 + quad*4 + reg, q-row = lr.
    f32x4 sH[2], sL[2];
    sH[0] = zf; sH[1] = zf; sL[0] = zf; sL[1] = zf;
#pragma unroll
    for (int c = 0; c < 4; c++)
#pragma unroll
      for (int ct = 0; ct < 2; ct++) {
        const int f = c * 2 + ct;
        sH[ct] = __builtin_amdgcn_mfma_f32_16x16x32_f16(kfC[f].h8, qh[c], sH[ct], 0, 0, 0);
        sL[ct] = __builtin_amdgcn_mfma_f32_16x16x32_f16(kfC[f].h8, ql[c], sL[ct], 0, 0, 0);
      }

    if (kt + 1 < NTILE) loadM(kt + 1, mp);
    __builtin_amdgcn_sched_barrier(0);

    // ---- max-free softmax, fully in registers ----
    float pv[2][4];
#pragma unroll
    for (int ct = 0; ct < 2; ct++) {
      const float* mf = (const float*)&mu[ct];
#pragma unroll
      for (int reg = 0; reg < 4; reg++) {
        float p = __expf(sH[ct][reg] + sL[ct][reg] + mf[reg]);
        l_part += p;
        pv[ct][reg] = p;
      }
    }

    // ---- pack P -> PV A-fragment in-lane (zero shuffles, zero LDS) ----
    FragU A;
    A.u[0] = pk_bf16(pv[0][0], pv[0][1]);
    A.u[1] = pk_bf16(pv[0][2], pv[0][3]);
    A.u[2] = pk_bf16(pv[1][0], pv[1][1]);
    A.u[3] = pk_bf16(pv[1][2], pv[1][3]);

    // ---- O += P * V: 8 independent MFMAs over d ----
#pragma unroll
    for (int nb = 0; nb < 8; nb++)
      o[nb] = __builtin_amdgcn_mfma_f32_16x16x32_bf16(A.s8, vf[nb].s8, o[nb], 0, 0, 0);

    if (kt + 1 < NTILE) loadV(kt + 1);   // WAR-safe: PV already issued
    __builtin_amdgcn_sched_barrier(0);
  };

  for (int kt = 0; kt < NTILE; kt += 2) {
    body(kt,     kfA, kfB, mA, mB);
    body(kt + 1, kfB, kfA, mB, mA);
  }

  // ---- epilogue: fully wave-internal (round-8 form) ----
  float lt = l_part;
  lt += __shfl_xor(lt, 16, 64);
  lt += __shfl_xor(lt, 32, 64);
  const float invl = 1.f / lt;           // valid at every lane for row = lr

  float inv_l[4];
#pragma unroll
  for (int reg = 0; reg < 4; reg++)
    inv_l[reg] = __shfl(invl, quad * 20 + reg, 64);   // lane quad*16 + (quad*4+reg)

  float gam[8], bet[8];
#pragma unroll
  for (int nb = 0; nb < 8; nb++) {
    gam[nb] = gammag[nb * 16 + lr];
    bet[nb] = betag[nb * 16 + lr];
  }

#pragma unroll
  for (int reg = 0; reg < 4; reg++) {
    float s1 = 0.f, s2 = 0.f;
#pragma unroll
    for (int nb = 0; nb < 8; nb++) {
      float v = o[nb][reg] * inv_l[reg];
      o[nb][reg] = v;
      s1 += v; s2 += v * v;
    }
#pragma unroll
    for (int m = 1; m <= 8; m <<= 1) {
      s1 += __shfl_xor(s1, m, 64);
      s2 += __shfl_xor(s2, m, 64);
    }
    const float mean = s1 * (1.f / 128.f);
    const float var  = s2 * (1.f / 128.f) - mean * mean;
    const float rstd = rsqrtf(var + LN_EPS);

    float* op = outg + ((size_t)b * LQ_ + q0 + w * 16 + quad * 4 + reg) * D_ + lr;
#pragma unroll
    for (int nb = 0; nb < 8; nb++)
      op[nb * 16] = (o[nb][reg] - mean) * rstd * gam[nb] + bet[nb];
  }
}

extern "C" void kernel_launch(void* const* d_in, const int* in_sizes, int n_in,
                              void* d_out, int out_size, void* d_ws, size_t ws_size,
                              hipStream_t stream) {
  const float* q     = (const float*)d_in[0];
  const float* k     = (const float*)d_in[1];
  const float* v     = (const float*)d_in[2];
  const float* mask  = (const float*)d_in[3];
  const float* gamma = (const float*)d_in[4];
  const float* beta  = (const float*)d_in[5];
  float* out = (float*)d_out;

  unsigned short* khg = (unsigned short*)d_ws;
  unsigned int*   vtg = (unsigned int*)((char*)d_ws + VT_OFF);

  conv_kv<<<dim3(B_ * NTILE), dim3(256), 0, stream>>>(k, v, khg, vtg);
  attn_ln_mfma<<<dim3(512), dim3(256), 0, stream>>>(q, mask, gamma, beta,
                                                    khg, vtg, out);
}

// Round 12
// 181.513 us; speedup vs baseline: 1.1276x; 1.1159x over previous
//
#include <hip/hip_runtime.h>
#include <hip/hip_bf16.h>
#include <hip/hip_fp16.h>
#include <math.h>

#define LQ_  2048
#define LK_  2048
#define D_   128
#define B_   16
#define LN_EPS 1e-5f
#define TK_  32
#define NTILE (LK_ / TK_)
#define NPAIR (NTILE / 2)
#define LOG2E 1.4426950408889634f

// Pre-converted tile images in workspace (round-8 layouts):
#define KH_TILE_US 4096          // 32 rows x 128 d fp16 swizzled (8192 B)
#define VT_TILE_U  2048          // 128 d x 16 slot uint, PV-permuted (8192 B)
#define KH_BYTES   ((size_t)B_ * NTILE * KH_TILE_US * 2)   // 8,388,608
#define VT_OFF     KH_BYTES                                 // 8,388,608
// total ws: 16,777,216 B

typedef __attribute__((ext_vector_type(8))) short short8;
typedef __attribute__((ext_vector_type(8))) _Float16 half8;
typedef __attribute__((ext_vector_type(4))) float f32x4;

union FragU { uint4 u4; short8 s8; half8 h8; unsigned int u[4]; };

__device__ __forceinline__ unsigned int pk_bf16(float a, float b) {
  __hip_bfloat162 h = __float22bfloat162_rn(make_float2(a, b));
  unsigned int u;
  __builtin_memcpy(&u, &h, 4);
  return u;
}
__device__ __forceinline__ unsigned int pk_f16(float a, float b) {
  __half2 h = __floats2half2_rn(a, b);
  unsigned int u;
  __builtin_memcpy(&u, &h, 4);
  return u;
}
__device__ __forceinline__ float f16_lo(unsigned int u) {
  unsigned short s = (unsigned short)(u & 0xffffu);
  __half h; __builtin_memcpy(&h, &s, 2); return __half2float(h);
}
__device__ __forceinline__ float f16_hi(unsigned int u) {
  unsigned short s = (unsigned short)(u >> 16);
  __half h; __builtin_memcpy(&h, &s, 2); return __half2float(h);
}

// K tiles: ushort [32 rows][128 d], 16B(8-elem)-chunk XOR swizzle by row.
__device__ __forceinline__ int idxK(int row, int d) {
  return row * 128 + ((((d >> 3) ^ row) & 15) << 3) + (d & 7);
}
// Vt: uint [128 d][16 slots]; 16B chunk rotation p = (g + (d>>1)) & 3.
// Slot->kp mapping is the PV-permuted order (see conv_kv emit).
__device__ __forceinline__ int idxVt(int d, int slot) {
  return d * 16 + ((((slot >> 2) + (d >> 1)) & 3) << 2) + (slot & 3);
}

// Barrier that drains this wave's pair-stage DMA (stage ops are the oldest;
// the 4 newest vm ops -- prefetched mask float4 loads -- stay in flight).
__device__ __forceinline__ void barrier_stage() {
  asm volatile("s_waitcnt vmcnt(4) lgkmcnt(0)\n\ts_barrier" ::: "memory");
}

__device__ __forceinline__ void gld_lds16(const void* g, void* l) {
  __builtin_amdgcn_global_load_lds((const __attribute__((address_space(1))) void*)g,
                                   (__attribute__((address_space(3))) void*)l, 16, 0, 0);
}

// ---------------- pre-pass: K -> fp16 swizzled, V -> bf16-pair Vt ----------
__global__ __launch_bounds__(256) void conv_kv(
    const float* __restrict__ kg, const float* __restrict__ vg,
    unsigned short* __restrict__ khg, unsigned int* __restrict__ vtg)
{
  __shared__ float Vlt[128 * 33];   // V tile transposed, +1-pad rows
  const int tid = threadIdx.x;
  const int blk = blockIdx.x;          // b*64 + t
  const int b = blk >> 6;
  const int t = blk & 63;

  const float* ks = kg + ((size_t)b * LK_ + t * 32) * D_;
  const float* vs = vg + ((size_t)b * LK_ + t * 32) * D_;
  unsigned short* kh = khg + (size_t)blk * KH_TILE_US;
  unsigned int*   vt = vtg + (size_t)blk * VT_TILE_U;

  // K: 512 (row, 8-chunk) items; coalesced reads, 16B swizzled writes.
#pragma unroll
  for (int it = 0; it < 2; it++) {
    const int item = tid + it * 256;
    const int row = item >> 4;
    const int c8  = item & 15;
    const float* p = ks + row * D_ + c8 * 8;
    float4 x = *(const float4*)(p);
    float4 y = *(const float4*)(p + 4);
    FragU H;
    H.u[0] = pk_f16(x.x, x.y); H.u[1] = pk_f16(x.z, x.w);
    H.u[2] = pk_f16(y.x, y.y); H.u[3] = pk_f16(y.z, y.w);
    *(uint4*)&kh[idxK(row, c8 * 8)] = H.u4;
  }

  // V tile -> LDS transposed (coalesced global reads).
#pragma unroll
  for (int i = 0; i < 4; i++) {
    const int item = tid + i * 256;
    const int r = item >> 5, c4 = item & 31;
    float4 x = *(const float4*)&vs[r * D_ + c4 * 4];
    Vlt[(c4 * 4 + 0) * 33 + r] = x.x;
    Vlt[(c4 * 4 + 1) * 33 + r] = x.y;
    Vlt[(c4 * 4 + 2) * 33 + r] = x.z;
    Vlt[(c4 * 4 + 3) * 33 + r] = x.w;
  }
  __syncthreads();

  // Emit Vt image linearly (coalesced writes); inverse-map phys slot -> kp.
#pragma unroll
  for (int i = 0; i < 8; i++) {
    const int o = tid + i * 256;
    const int d = o >> 4, sp = o & 15;
    const int gl = ((sp >> 2) - (d >> 1)) & 3;
    const int c  = sp & 3;
    const int kp = 2 * gl + ((c >> 1) << 3) + (c & 1);
    vt[o] = pk_bf16(Vlt[d * 33 + 2 * kp], Vlt[d * 33 + 2 * kp + 1]);
  }
}

// ---------------- main fused attention + LN ----------------
// Stage one PAIR of tiles (16 KB K + 16 KB Vt) via global_load_lds:
// 8 x 1KiB 16B-wide ops per wave; 4 cooperating waves cover 32 KB.
__device__ __forceinline__ void stage_pair(int w, int lane,
    const unsigned short* khT, const unsigned int* vtT,
    int tp, char* khs, char* vts)
{
  const char* gkh = (const char*)khT + (size_t)tp * 16384;
  const char* gvt = (const char*)vtT + (size_t)tp * 16384;
#pragma unroll
  for (int c = 0; c < 4; c++) {
    const int off = (w + 4 * c) << 10;            // 1 KiB chunks
    gld_lds16(gkh + off + lane * 16, khs + off);
    gld_lds16(gvt + off + lane * 16, vts + off);
  }
}

__global__ __launch_bounds__(256, 2) void attn_ln_mfma(
    const float* __restrict__ qg, const float* __restrict__ maskg,
    const float* __restrict__ gammag, const float* __restrict__ betag,
    const unsigned short* __restrict__ khg, const unsigned int* __restrict__ vtg,
    float* __restrict__ outg)
{
  __shared__ unsigned short KhS[2][64 * 128];   // 32 KB (fp16, 2 sub-tiles)
  __shared__ unsigned int   VtW[2][64 * 64];    // 32 KB (2 sub-tiles)
  // total 65,536 B -> 2 blocks/CU

  const int tid  = threadIdx.x;
  const int w    = tid >> 6;     // wave owns q-rows [q0 + w*16, +16)
  const int lane = tid & 63;
  const int quad = lane >> 4;
  const int lr   = lane & 15;

  // XCD swizzle: blocks on XCD x serve batches {2x,2x+1} -> K/V L2-resident.
  const int id   = blockIdx.x;
  const int xcd  = id & 7;
  const int slot = id >> 3;
  const int b    = xcd * 2 + (slot >> 5);
  const int q0   = (slot & 31) * 64;

  const unsigned short* khT = khg + (size_t)b * NTILE * KH_TILE_US;
  const unsigned int*   vtT = vtg + (size_t)b * NTILE * VT_TILE_U;

  // mask row for this lane's q-row (= lr in swapped layout), quad's k-cols.
  const float* mrow = maskg + (size_t)(q0 + w * 16 + lr) * LK_ + quad * 4;

  // ---- issue pair-0 stage DMA + mask(0) prefetch (fly during Q build) ----
  stage_pair(w, lane, khT, vtT, 0, (char*)&KhS[0][0], (char*)&VtW[0][0]);
  float4 mA[4], mB[4];
  mA[0] = *(const float4*)(mrow);
  mA[1] = *(const float4*)(mrow + 16);
  mA[2] = *(const float4*)(mrow + 32);
  mA[3] = *(const float4*)(mrow + 48);

  // ---- Q fragments (fp16 hi/lo), PRE-SCALED by log2(e); row = w*16+lr ----
  half8 qh[4], ql[4];
  {
    const float* qrow = qg + ((size_t)b * LQ_ + q0 + w * 16 + lr) * D_ + quad * 8;
#pragma unroll
    for (int c = 0; c < 4; c++) {
      float4 x = *(const float4*)(qrow + c * 32);
      float4 y = *(const float4*)(qrow + c * 32 + 4);
      x.x *= LOG2E; x.y *= LOG2E; x.z *= LOG2E; x.w *= LOG2E;
      y.x *= LOG2E; y.y *= LOG2E; y.z *= LOG2E; y.w *= LOG2E;
      FragU H, L;
      H.u[0] = pk_f16(x.x, x.y); H.u[1] = pk_f16(x.z, x.w);
      H.u[2] = pk_f16(y.x, y.y); H.u[3] = pk_f16(y.z, y.w);
      L.u[0] = pk_f16(x.x - f16_lo(H.u[0]), x.y - f16_hi(H.u[0]));
      L.u[1] = pk_f16(x.z - f16_lo(H.u[1]), x.w - f16_hi(H.u[1]));
      L.u[2] = pk_f16(y.x - f16_lo(H.u[2]), y.y - f16_hi(H.u[2]));
      L.u[3] = pk_f16(y.z - f16_lo(H.u[3]), y.w - f16_hi(H.u[3]));
      qh[c] = H.h8; ql[c] = L.h8;
    }
  }

  float l_part = 0.f;            // sum of p over this lane's k-cols, row = lr
  f32x4 o[8];                    // [nb]: q-row = quad*4+reg, d = nb*16+lr
  const f32x4 zf = {0.f, 0.f, 0.f, 0.f};
#pragma unroll
  for (int n = 0; n < 8; n++) o[n] = zf;

  // One sub-tile: QK (swapped operands) -> in-register softmax -> PV.
  // khc/vtc point at the sub-tile base; mu0/mu1 are its two mask float4s.
  auto subtile = [&](const unsigned short* khc, const unsigned int* vtc,
                     const float4& mu0, const float4& mu1)
      __attribute__((always_inline)) -> void {
    f32x4 sH[2], sL[2];
    sH[0] = zf; sH[1] = zf; sL[0] = zf; sL[1] = zf;
#pragma unroll
    for (int c = 0; c < 4; c++)
#pragma unroll
      for (int ct = 0; ct < 2; ct++) {
        FragU kh;
        kh.u4 = *(const uint4*)&khc[idxK(ct * 16 + lr, c * 32 + quad * 8)];
        sH[ct] = __builtin_amdgcn_mfma_f32_16x16x32_f16(kh.h8, qh[c], sH[ct], 0, 0, 0);
        sL[ct] = __builtin_amdgcn_mfma_f32_16x16x32_f16(kh.h8, ql[c], sL[ct], 0, 0, 0);
      }

    // Bv reads: LDS latency overlaps the exp chain.
    FragU Bv[8];
#pragma unroll
    for (int nb = 0; nb < 8; nb++)
      Bv[nb].u4 = *(const uint4*)&vtc[idxVt(nb * 16 + lr, quad * 4)];

    // max-free softmax (base-2; Q pre-scaled, mask scaled here via fma).
    float pv[2][4];
    const float* mf0 = (const float*)&mu0;
    const float* mf1 = (const float*)&mu1;
#pragma unroll
    for (int reg = 0; reg < 4; reg++) {
      float p0 = exp2f(fmaf(mf0[reg], LOG2E, sH[0][reg] + sL[0][reg]));
      float p1 = exp2f(fmaf(mf1[reg], LOG2E, sH[1][reg] + sL[1][reg]));
      l_part += p0; l_part += p1;
      pv[0][reg] = p0; pv[1][reg] = p1;
    }

    // pack P -> PV A-fragment in-lane (zero shuffles, zero LDS).
    FragU A;
    A.u[0] = pk_bf16(pv[0][0], pv[0][1]);
    A.u[1] = pk_bf16(pv[0][2], pv[0][3]);
    A.u[2] = pk_bf16(pv[1][0], pv[1][1]);
    A.u[3] = pk_bf16(pv[1][2], pv[1][3]);

    // O += P * V: 8 independent MFMAs over d.
#pragma unroll
    for (int nb = 0; nb < 8; nb++)
      o[nb] = __builtin_amdgcn_mfma_f32_16x16x32_bf16(A.s8, Bv[nb].s8, o[nb], 0, 0, 0);
  };

  // One pair body: ONE barrier per 2 sub-tiles; sub-tiles are independent
  // streams inside the region (softmax0/PV0 overlap QK1 at the scheduler's
  // discretion -- no sync between them).
  auto body = [&](int tp, int cur, float4 (&mu)[4], float4 (&mp)[4])
      __attribute__((always_inline)) -> void {
    const unsigned short* khc = &KhS[cur][0];
    const unsigned int*   vtc = &VtW[cur][0];

    // All waves past previous pair's LDS reads; this wave's stage(tp) done.
    // The 4 newest vm ops (mask(tp) float4 loads) stay in flight.
    barrier_stage();

    // ---- issue NEXT pair stage (8 vm) + NEXT mask prefetch (4 vm) ----
    if (tp + 1 < NPAIR) {
      stage_pair(w, lane, khT, vtT, tp + 1,
                 (char*)&KhS[cur ^ 1][0], (char*)&VtW[cur ^ 1][0]);
      const float* mn = mrow + (size_t)(tp + 1) * 64;
      mp[0] = *(const float4*)(mn);
      mp[1] = *(const float4*)(mn + 16);
      mp[2] = *(const float4*)(mn + 32);
      mp[3] = *(const float4*)(mn + 48);
    }

    subtile(khc,        vtc,        mu[0], mu[1]);
    subtile(khc + 4096, vtc + 2048, mu[2], mu[3]);
  };

  for (int tp = 0; tp < NPAIR; tp += 2) {
    body(tp,     0, mA, mB);   // consumes mask in mA, prefetches into mB
    body(tp + 1, 1, mB, mA);   // consumes mask in mB, prefetches into mA
  }

  // ---- epilogue: fully wave-internal (round-8 form) ----
  float lt = l_part;
  lt += __shfl_xor(lt, 16, 64);
  lt += __shfl_xor(lt, 32, 64);
  const float invl = 1.f / lt;           // valid at every lane for row = lr

  float inv_l[4];
#pragma unroll
  for (int reg = 0; reg < 4; reg++)
    inv_l[reg] = __shfl(invl, quad * 20 + reg, 64);   // lane quad*16 + (quad*4+reg)

  float gam[8], bet[8];
#pragma unroll
  for (int nb = 0; nb < 8; nb++) {
    gam[nb] = gammag[nb * 16 + lr];
    bet[nb] = betag[nb * 16 + lr];
  }

#pragma unroll
  for (int reg = 0; reg < 4; reg++) {
    float s1 = 0.f, s2 = 0.f;
#pragma unroll
    for (int nb = 0; nb < 8; nb++) {
      float v = o[nb][reg] * inv_l[reg];
      o[nb][reg] = v;
      s1 += v; s2 += v * v;
    }
#pragma unroll
    for (int m = 1; m <= 8; m <<= 1) {
      s1 += __shfl_xor(s1, m, 64);
      s2 += __shfl_xor(s2, m, 64);
    }
    const float mean = s1 * (1.f / 128.f);
    const float var  = s2 * (1.f / 128.f) - mean * mean;
    const float rstd = rsqrtf(var + LN_EPS);

    float* op = outg + ((size_t)b * LQ_ + q0 + w * 16 + quad * 4 + reg) * D_ + lr;
#pragma unroll
    for (int nb = 0; nb < 8; nb++)
      op[nb * 16] = (o[nb][reg] - mean) * rstd * gam[nb] + bet[nb];
  }
}

extern "C" void kernel_launch(void* const* d_in, const int* in_sizes, int n_in,
                              void* d_out, int out_size, void* d_ws, size_t ws_size,
                              hipStream_t stream) {
  const float* q     = (const float*)d_in[0];
  const float* k     = (const float*)d_in[1];
  const float* v     = (const float*)d_in[2];
  const float* mask  = (const float*)d_in[3];
  const float* gamma = (const float*)d_in[4];
  const float* beta  = (const float*)d_in[5];
  float* out = (float*)d_out;

  unsigned short* khg = (unsigned short*)d_ws;
  unsigned int*   vtg = (unsigned int*)((char*)d_ws + VT_OFF);

  conv_kv<<<dim3(B_ * NTILE), dim3(256), 0, stream>>>(k, v, khg, vtg);
  attn_ln_mfma<<<dim3(512), dim3(256), 0, stream>>>(q, mask, gamma, beta,
                                                    khg, vtg, out);
}